// Round 3
// baseline (1601.138 us; speedup 1.0000x reference)
//
#include <hip/hip_runtime.h>

typedef __bf16 bfx8 __attribute__((ext_vector_type(8)));
typedef __bf16 bfx4 __attribute__((ext_vector_type(4)));
typedef float  f32x4 __attribute__((ext_vector_type(4)));

#define MFMA16(a,b,c) __builtin_amdgcn_mfma_f32_16x16x32_bf16((a),(b),(c),0,0,0)

static constexpr int BATCH = 8;
static constexpr int NTOK  = 4096;   // 64*64 spatial
static constexpr int CH    = 512;
static constexpr float GN_EPS = 1e-5f;
static constexpr float ATT_SCALE = 0.044194173824159216f; // 512^-0.5

// ---------------------------------------------------------------------------
// prep: fp32 weights -> bf16 transposed (wT[n][c] = w[c][n]); concat fp32 biases.
// grid (16,16,4) z: 0=wq 1=wk 2=wv 3=wo. block 256.
// ---------------------------------------------------------------------------
__global__ __launch_bounds__(256)
void prep_weights(const float* __restrict__ wq, const float* __restrict__ wk,
                  const float* __restrict__ wv, const float* __restrict__ wo,
                  const float* __restrict__ bq, const float* __restrict__ bk,
                  const float* __restrict__ bv,
                  __bf16* __restrict__ wqkvT, __bf16* __restrict__ woT,
                  float* __restrict__ bqkv)
{
    __shared__ __bf16 t[32][36];
    const int z  = blockIdx.z;
    const float* src = (z == 0) ? wq : (z == 1) ? wk : (z == 2) ? wv : wo;
    const int c0 = blockIdx.x * 32, n0 = blockIdx.y * 32;
    const int tid = threadIdx.x;
    const int r = tid >> 3, c4 = (tid & 7) * 4;

    f32x4 in = *(const f32x4*)&src[(size_t)(c0 + r) * 512 + n0 + c4];
    bfx4 tv;
#pragma unroll
    for (int i = 0; i < 4; ++i) tv[i] = (__bf16)in[i];
    *(bfx4*)&t[r][c4] = tv;
    __syncthreads();
    bfx4 o;
#pragma unroll
    for (int i = 0; i < 4; ++i) o[i] = t[c4 + i][r];
    if (z < 3)
        *(bfx4*)&wqkvT[((size_t)(z * 512 + n0 + r)) * 512 + c0 + c4] = o;
    else
        *(bfx4*)&woT[((size_t)(n0 + r)) * 512 + c0 + c4] = o;

    if (z < 3 && blockIdx.x == 0 && blockIdx.y == 0) {
        const float* bs = (z == 0) ? bq : (z == 1) ? bk : bv;
        bqkv[z * 512 + tid]       = bs[tid];
        bqkv[z * 512 + tid + 256] = bs[tid + 256];
    }
}

// ---------------------------------------------------------------------------
// GroupNorm statistics: one block per (g, b). Writes per-channel fused
// scale/bias:  h[ch] = x[ch]*scA[b][ch] + biA[b][ch].  grid (32, 8), block 256.
// ---------------------------------------------------------------------------
__global__ __launch_bounds__(256)
void gn_stats(const float* __restrict__ x, const float* __restrict__ gs,
              const float* __restrict__ gb,
              float* __restrict__ scA, float* __restrict__ biA)
{
    const int g = blockIdx.x, b = blockIdx.y;
    const int tid = threadIdx.x;
    const int half = tid & 1;
    const size_t base = (size_t)b * NTOK * CH + g * 16 + half * 8;

    float sum = 0.f, sumsq = 0.f;
    for (int i = tid; i < 2 * NTOK; i += 256) {
        const int s = i >> 1;
        f32x4 v0 = *(const f32x4*)&x[base + (size_t)s * CH];
        f32x4 v1 = *(const f32x4*)&x[base + (size_t)s * CH + 4];
#pragma unroll
        for (int j = 0; j < 4; ++j) {
            sum += v0[j] + v1[j];
            sumsq += v0[j] * v0[j] + v1[j] * v1[j];
        }
    }
#pragma unroll
    for (int o = 32; o; o >>= 1) { sum += __shfl_down(sum, o); sumsq += __shfl_down(sumsq, o); }
    __shared__ float red[8];
    __shared__ float stats[2];
    const int w = tid >> 6;
    if ((tid & 63) == 0) { red[w] = sum; red[4 + w] = sumsq; }
    __syncthreads();
    if (tid == 0) {
        float s1 = red[0] + red[1] + red[2] + red[3];
        float s2 = red[4] + red[5] + red[6] + red[7];
        float mean = s1 * (1.f / 65536.f);
        float var  = s2 * (1.f / 65536.f) - mean * mean;
        stats[0] = mean; stats[1] = rsqrtf(var + GN_EPS);
    }
    __syncthreads();
    if (tid < 16) {
        const int ch = g * 16 + tid;
        const float sc = gs[ch] * stats[1];
        scA[b * 512 + ch] = sc;
        biA[b * 512 + ch] = gb[ch] - stats[0] * sc;
    }
}

// ---------------------------------------------------------------------------
// Fused GN-normalize + QKV GEMM.  A = x*sc+bi (fp32->bf16), B = wqkvT rows.
//   n in [0,1024): qk[m][n] = C + bias
//   n in [1024,1536): C+bias -> transposed into vT[b][ch][tok] via LDS
// 128x128 tile, BK=32, 4 waves. grid (M/128, 12), block 256.
// ---------------------------------------------------------------------------
__global__ __launch_bounds__(256)
void gemm_qkv(const float* __restrict__ x, const float* __restrict__ scA,
              const float* __restrict__ biA, const __bf16* __restrict__ Bt,
              const float* __restrict__ bias,
              __bf16* __restrict__ qk, __bf16* __restrict__ vT)
{
    const int bm = blockIdx.x * 128, bn = blockIdx.y * 128;
    const int tid = threadIdx.x;
    const int w = tid >> 6, lane = tid & 63, quad = lane >> 4, l15 = lane & 15;
    const int wm = (w >> 1) * 64, wn = (w & 1) * 64;
    const int brow = bm >> 12;                  // batch of this m-tile

    __shared__ __bf16 sAB[2][128][40];          // As = sAB[0], Bs = sAB[1]

    f32x4 acc[4][4];
#pragma unroll
    for (int i = 0; i < 4; ++i)
#pragma unroll
        for (int j = 0; j < 4; ++j) acc[i][j] = (f32x4){0.f, 0.f, 0.f, 0.f};

    const int sr = tid >> 2, scol = (tid & 3) * 8;
    for (int k0 = 0; k0 < 512; k0 += 32) {
        __syncthreads();
        {   // A: load fp32 x, apply GN scale/bias, stage bf16
            const float* scp = scA + brow * 512 + k0 + scol;
            const float* bip = biA + brow * 512 + k0 + scol;
            f32x4 s0v = *(const f32x4*)&scp[0], s1v = *(const f32x4*)&scp[4];
            f32x4 b0v = *(const f32x4*)&bip[0], b1v = *(const f32x4*)&bip[4];
            f32x4 xa0 = *(const f32x4*)&x[(size_t)(bm + sr) * 512 + k0 + scol];
            f32x4 xa1 = *(const f32x4*)&x[(size_t)(bm + sr) * 512 + k0 + scol + 4];
            f32x4 xb0 = *(const f32x4*)&x[(size_t)(bm + sr + 64) * 512 + k0 + scol];
            f32x4 xb1 = *(const f32x4*)&x[(size_t)(bm + sr + 64) * 512 + k0 + scol + 4];
            bfx8 ha, hb;
#pragma unroll
            for (int j = 0; j < 4; ++j) {
                ha[j]     = (__bf16)(xa0[j] * s0v[j] + b0v[j]);
                ha[4 + j] = (__bf16)(xa1[j] * s1v[j] + b1v[j]);
                hb[j]     = (__bf16)(xb0[j] * s0v[j] + b0v[j]);
                hb[4 + j] = (__bf16)(xb1[j] * s1v[j] + b1v[j]);
            }
            *(bfx8*)&sAB[0][sr][scol]      = ha;
            *(bfx8*)&sAB[0][sr + 64][scol] = hb;
        }
        *(bfx8*)&sAB[1][sr][scol]      = *(const bfx8*)&Bt[(size_t)(bn + sr) * 512 + k0 + scol];
        *(bfx8*)&sAB[1][sr + 64][scol] = *(const bfx8*)&Bt[(size_t)(bn + sr + 64) * 512 + k0 + scol];
        __syncthreads();
        bfx8 af[4], bfr[4];
#pragma unroll
        for (int mi = 0; mi < 4; ++mi) af[mi]  = *(const bfx8*)&sAB[0][wm + mi * 16 + l15][quad * 8];
#pragma unroll
        for (int ni = 0; ni < 4; ++ni) bfr[ni] = *(const bfx8*)&sAB[1][wn + ni * 16 + l15][quad * 8];
#pragma unroll
        for (int mi = 0; mi < 4; ++mi)
#pragma unroll
            for (int ni = 0; ni < 4; ++ni)
                acc[mi][ni] = MFMA16(af[mi], bfr[ni], acc[mi][ni]);
    }

    if (blockIdx.y < 8) {
        // q/k epilogue: direct store, D row = quad*4+reg, col = l15
#pragma unroll
        for (int ni = 0; ni < 4; ++ni) {
            const int col = bn + wn + ni * 16 + l15;
            const float bv = bias[col];
#pragma unroll
            for (int mi = 0; mi < 4; ++mi)
#pragma unroll
                for (int rr = 0; rr < 4; ++rr) {
                    const int row = bm + wm + mi * 16 + quad * 4 + rr;
                    qk[(size_t)row * 1024 + col] = (__bf16)(acc[mi][ni][rr] + bv);
                }
        }
    } else {
        // v epilogue: transpose 128x128 tile into vT[b][ch][tok] via LDS
        const int vch0 = bn - 1024;
        const int tokbase = bm & 4095;
        __bf16* tb = &sAB[0][0][0];             // reuse As+Bs: [64][136] bf16
        __syncthreads();                         // all waves done reading frags
#pragma unroll
        for (int chunk = 0; chunk < 2; ++chunk) {
            if ((w & 1) == chunk) {
#pragma unroll
                for (int ni = 0; ni < 4; ++ni) {
                    const int chc = ni * 16 + l15;               // 0..63 in chunk
                    const float bv = bias[bn + chunk * 64 + chc];
#pragma unroll
                    for (int mi = 0; mi < 4; ++mi)
#pragma unroll
                        for (int rr = 0; rr < 4; ++rr) {
                            const int tok = wm + mi * 16 + quad * 4 + rr;
                            tb[chc * 136 + tok] = (__bf16)(acc[mi][ni][rr] + bv);
                        }
                }
            }
            __syncthreads();
            {   // cooperative coalesced store of the 64ch x 128tok chunk
                const int chn = tid >> 2, t0 = (tid & 3) * 32;
                const size_t gb0 =
                    ((size_t)(brow * 512 + vch0 + chunk * 64 + chn)) * 4096 + tokbase;
#pragma unroll
                for (int u = 0; u < 4; ++u)
                    *(bfx8*)&vT[gb0 + t0 + u * 8] = *(const bfx8*)&tb[chn * 136 + t0 + u * 8];
            }
            __syncthreads();
        }
    }
}

// ---------------------------------------------------------------------------
// Flash attention + fused output projection + residual (fp32 out).
// TQ=64 rows/block, TK=32/iter, 4 waves; wave w owns S rows [w*16,w*16+16)
// with in-register online softmax; O cols split by wave (128 each).
// Phase 2: out = O*woT^T + bo + x.  grid (NTOK/64, B), block 256.
// ---------------------------------------------------------------------------
__global__ __launch_bounds__(256)
void attn_fused(const __bf16* __restrict__ qk, const __bf16* __restrict__ vT,
                const __bf16* __restrict__ woT, const float* __restrict__ bo,
                const float* __restrict__ x, float* __restrict__ out)
{
    const int bb = blockIdx.y;
    const int q0 = blockIdx.x * 64;
    const int tid = threadIdx.x;
    const int w = tid >> 6, lane = tid & 63, quad = lane >> 4, l15 = lane & 15;

    __shared__ __attribute__((aligned(16))) unsigned char smem[79872];
    __bf16 (*Ks)[520] = (__bf16(*)[520])smem;                 // 32x520  (33280 B)
    __bf16 (*Vs)[40]  = (__bf16(*)[40])(smem + 33280);        // 512x40  (40960 B)
    __bf16 (*Ph)[40]  = (__bf16(*)[40])(smem + 74240);        // 64x40   (5120 B)
    float* abuf = (float*)(smem + 79360);                     // 64 f32
    float* lbuf = (float*)(smem + 79616);                     // 64 f32
    __bf16 (*Obuf)[520] = (__bf16(*)[520])smem;               // 64x520, post-loop

    // Q rows for this wave's S strip, full K=512, in registers
    bfx8 qf[16];
    {
        const __bf16* qptr = qk + ((size_t)(bb * NTOK + q0 + w * 16 + l15)) * 1024;
#pragma unroll
        for (int kk = 0; kk < 16; ++kk)
            qf[kk] = *(const bfx8*)&qptr[kk * 32 + quad * 8];
    }

    f32x4 oacc[4][8];
#pragma unroll
    for (int i = 0; i < 4; ++i)
#pragma unroll
        for (int j = 0; j < 8; ++j) oacc[i][j] = (f32x4){0.f, 0.f, 0.f, 0.f};
    float mrow[4] = {-1e30f, -1e30f, -1e30f, -1e30f};
    float lrow[4] = {0.f, 0.f, 0.f, 0.f};

    for (int kt = 0; kt < NTOK / 32; ++kt) {
        __syncthreads();
        {   // stage K-tile: 32 rows x 512ch from qk cols [512,1024)
            const int r = tid >> 3, c0 = (tid & 7) * 64;
            const __bf16* kp = qk + ((size_t)(bb * NTOK + kt * 32 + r)) * 1024 + 512 + c0;
#pragma unroll
            for (int u = 0; u < 8; ++u)
                *(bfx8*)&Ks[r][c0 + u * 8] = *(const bfx8*)&kp[u * 8];
        }
        {   // stage V^T tile: 512 rows(ch) x 32(tok)
            const int c = tid >> 2, jo = (tid & 3) * 8;
#pragma unroll
            for (int p = 0; p < 8; ++p)
                *(bfx8*)&Vs[c + p * 64][jo] =
                    *(const bfx8*)&vT[((size_t)(bb * 512 + c + p * 64)) * NTOK + kt * 32 + jo];
        }
        __syncthreads();

        // S strip: rows [w*16,w*16+16) x 32 cols
        f32x4 s0 = (f32x4){0.f, 0.f, 0.f, 0.f}, s1 = (f32x4){0.f, 0.f, 0.f, 0.f};
#pragma unroll
        for (int kk = 0; kk < 16; ++kk) {
            bfx8 kb0 = *(const bfx8*)&Ks[l15][kk * 32 + quad * 8];
            bfx8 kb1 = *(const bfx8*)&Ks[16 + l15][kk * 32 + quad * 8];
            s0 = MFMA16(qf[kk], kb0, s0);
            s1 = MFMA16(qf[kk], kb1, s1);
        }
#pragma unroll
        for (int r = 0; r < 4; ++r) {
            float v0 = s0[r] * ATT_SCALE;
            float v1 = s1[r] * ATT_SCALE;
            float mx = fmaxf(v0, v1);
#pragma unroll
            for (int o = 1; o < 16; o <<= 1) mx = fmaxf(mx, __shfl_xor(mx, o));
            const float mnew = fmaxf(mrow[r], mx);
            const float al = __expf(mrow[r] - mnew);
            const float p0 = __expf(v0 - mnew);
            const float p1 = __expf(v1 - mnew);
            float ps = p0 + p1;
#pragma unroll
            for (int o = 1; o < 16; o <<= 1) ps += __shfl_xor(ps, o);
            lrow[r] = lrow[r] * al + ps;
            mrow[r] = mnew;
            const int row = w * 16 + quad * 4 + r;
            Ph[row][l15]      = (__bf16)p0;
            Ph[row][16 + l15] = (__bf16)p1;
            if (l15 == 0) abuf[row] = al;
        }
        __syncthreads();

        // O *= alpha;  O += P*V  (wave cols [w*128, w*128+128))
#pragma unroll
        for (int mt = 0; mt < 4; ++mt)
#pragma unroll
            for (int r = 0; r < 4; ++r) {
                const float al = abuf[mt * 16 + quad * 4 + r];
#pragma unroll
                for (int ct = 0; ct < 8; ++ct) oacc[mt][ct][r] *= al;
            }
        bfx8 pa[4];
#pragma unroll
        for (int mt = 0; mt < 4; ++mt)
            pa[mt] = *(const bfx8*)&Ph[mt * 16 + l15][quad * 8];
#pragma unroll
        for (int ct = 0; ct < 8; ++ct) {
            bfx8 vb = *(const bfx8*)&Vs[w * 128 + ct * 16 + l15][quad * 8];
#pragma unroll
            for (int mt = 0; mt < 4; ++mt)
                oacc[mt][ct] = MFMA16(pa[mt], vb, oacc[mt][ct]);
        }
    }

    // ---- phase 2: normalize, stage O, fused projection + bias + residual ----
    if (l15 == 0) {
#pragma unroll
        for (int r = 0; r < 4; ++r) lbuf[w * 16 + quad * 4 + r] = lrow[r];
    }
    __syncthreads();   // also fences last PV reads before Obuf aliases Ks/Vs
#pragma unroll
    for (int mt = 0; mt < 4; ++mt)
#pragma unroll
        for (int r = 0; r < 4; ++r) {
            const float linv = 1.f / lbuf[mt * 16 + quad * 4 + r];
#pragma unroll
            for (int ct = 0; ct < 8; ++ct)
                Obuf[mt * 16 + quad * 4 + r][w * 128 + ct * 16 + l15] =
                    (__bf16)(oacc[mt][ct][r] * linv);
        }
    __syncthreads();

    // wave w: out rows [w*16, w*16+16), all 512 cols.
    bfx8 af2[16];
#pragma unroll
    for (int k0 = 0; k0 < 16; ++k0)
        af2[k0] = *(const bfx8*)&Obuf[w * 16 + l15][k0 * 32 + quad * 8];

#pragma unroll 4
    for (int nt = 0; nt < 32; ++nt) {
        f32x4 a2 = (f32x4){0.f, 0.f, 0.f, 0.f};
#pragma unroll
        for (int k0 = 0; k0 < 16; ++k0) {
            bfx8 wb = *(const bfx8*)&woT[(size_t)(nt * 16 + l15) * 512 + k0 * 32 + quad * 8];
            a2 = MFMA16(af2[k0], wb, a2);
        }
        const int col = nt * 16 + l15;
        const float bv = bo[col];
#pragma unroll
        for (int rr = 0; rr < 4; ++rr) {
            const size_t idx =
                ((size_t)(bb * NTOK + q0 + w * 16 + quad * 4 + rr)) * 512 + col;
            out[idx] = a2[rr] + bv + x[idx];
        }
    }
}

// ---------------------------------------------------------------------------
extern "C" void kernel_launch(void* const* d_in, const int* in_sizes, int n_in,
                              void* d_out, int out_size, void* d_ws, size_t ws_size,
                              hipStream_t stream)
{
    const float* x  = (const float*)d_in[0];
    const float* gs = (const float*)d_in[1];
    const float* gb = (const float*)d_in[2];
    const float* wq = (const float*)d_in[3];
    const float* bq = (const float*)d_in[4];
    const float* wk = (const float*)d_in[5];
    const float* bk = (const float*)d_in[6];
    const float* wv = (const float*)d_in[7];
    const float* bv = (const float*)d_in[8];
    const float* wo = (const float*)d_in[9];
    const float* bo = (const float*)d_in[10];
    float* out = (float*)d_out;

    // workspace layout -- total 102,799,360 B (~98 MiB)
    char* ws = (char*)d_ws;
    __bf16* qk    = (__bf16*)(ws);                    //  67,108,864 B [32768][1024]
    __bf16* vT    = (__bf16*)(ws + 67108864);         //  33,554,432 B [8][512][4096]
    __bf16* wqkvT = (__bf16*)(ws + 100663296);        //   1,572,864 B [1536][512]
    __bf16* woT   = (__bf16*)(ws + 102236160);        //     524,288 B [512][512]
    float*  bqkv  = (float* )(ws + 102760448);        //       6,144 B [1536]
    float*  scA   = (float* )(ws + 102766592);        //      16,384 B [8][512]
    float*  biA   = (float* )(ws + 102782976);        //      16,384 B [8][512]

    prep_weights<<<dim3(16, 16, 4), 256, 0, stream>>>(wq, wk, wv, wo, bq, bk, bv,
                                                      wqkvT, woT, bqkv);
    gn_stats<<<dim3(32, BATCH), 256, 0, stream>>>(x, gs, gb, scA, biA);
    gemm_qkv<<<dim3(256, 12), 256, 0, stream>>>(x, scA, biA, wqkvT, bqkv, qk, vT);
    attn_fused<<<dim3(NTOK / 64, BATCH), 256, 0, stream>>>(qk, vT, woT, bo, x, out);
}

// Round 4
// 1199.857 us; speedup vs baseline: 1.3344x; 1.3344x over previous
//
#include <hip/hip_runtime.h>

typedef __bf16 bfx8 __attribute__((ext_vector_type(8)));
typedef __bf16 bfx4 __attribute__((ext_vector_type(4)));
typedef float  f32x4 __attribute__((ext_vector_type(4)));

#define MFMA16(a,b,c) __builtin_amdgcn_mfma_f32_16x16x32_bf16((a),(b),(c),0,0,0)

static constexpr int BATCH = 8;
static constexpr int NTOK  = 4096;   // 64*64 spatial
static constexpr int CH    = 512;
static constexpr float GN_EPS = 1e-5f;
static constexpr float ATT_SCALE = 0.044194173824159216f; // 512^-0.5

// ---------------------------------------------------------------------------
// prep: fp32 weights -> bf16 transposed (wT[n][c] = w[c][n]); concat fp32 biases.
// grid (16,16,4) z: 0=wq 1=wk 2=wv 3=wo. block 256.
// ---------------------------------------------------------------------------
__global__ __launch_bounds__(256)
void prep_weights(const float* __restrict__ wq, const float* __restrict__ wk,
                  const float* __restrict__ wv, const float* __restrict__ wo,
                  const float* __restrict__ bq, const float* __restrict__ bk,
                  const float* __restrict__ bv,
                  __bf16* __restrict__ wqkvT, __bf16* __restrict__ woT,
                  float* __restrict__ bqkv)
{
    __shared__ __bf16 t[32][36];
    const int z  = blockIdx.z;
    const float* src = (z == 0) ? wq : (z == 1) ? wk : (z == 2) ? wv : wo;
    const int c0 = blockIdx.x * 32, n0 = blockIdx.y * 32;
    const int tid = threadIdx.x;
    const int r = tid >> 3, c4 = (tid & 7) * 4;

    f32x4 in = *(const f32x4*)&src[(size_t)(c0 + r) * 512 + n0 + c4];
    bfx4 tv;
#pragma unroll
    for (int i = 0; i < 4; ++i) tv[i] = (__bf16)in[i];
    *(bfx4*)&t[r][c4] = tv;
    __syncthreads();
    bfx4 o;
#pragma unroll
    for (int i = 0; i < 4; ++i) o[i] = t[c4 + i][r];
    if (z < 3)
        *(bfx4*)&wqkvT[((size_t)(z * 512 + n0 + r)) * 512 + c0 + c4] = o;
    else
        *(bfx4*)&woT[((size_t)(n0 + r)) * 512 + c0 + c4] = o;

    if (z < 3 && blockIdx.x == 0 && blockIdx.y == 0) {
        const float* bs = (z == 0) ? bq : (z == 1) ? bk : bv;
        bqkv[z * 512 + tid]       = bs[tid];
        bqkv[z * 512 + tid + 256] = bs[tid + 256];
    }
}

// ---------------------------------------------------------------------------
// GroupNorm statistics: one block per (g, b). Writes per-channel fused
// scale/bias:  h[ch] = x[ch]*scA[b][ch] + biA[b][ch].  grid (32, 8), block 256.
// ---------------------------------------------------------------------------
__global__ __launch_bounds__(256)
void gn_stats(const float* __restrict__ x, const float* __restrict__ gs,
              const float* __restrict__ gb,
              float* __restrict__ scA, float* __restrict__ biA)
{
    const int g = blockIdx.x, b = blockIdx.y;
    const int tid = threadIdx.x;
    const int half = tid & 1;
    const size_t base = (size_t)b * NTOK * CH + g * 16 + half * 8;

    float sum = 0.f, sumsq = 0.f;
    for (int i = tid; i < 2 * NTOK; i += 256) {
        const int s = i >> 1;
        f32x4 v0 = *(const f32x4*)&x[base + (size_t)s * CH];
        f32x4 v1 = *(const f32x4*)&x[base + (size_t)s * CH + 4];
#pragma unroll
        for (int j = 0; j < 4; ++j) {
            sum += v0[j] + v1[j];
            sumsq += v0[j] * v0[j] + v1[j] * v1[j];
        }
    }
#pragma unroll
    for (int o = 32; o; o >>= 1) { sum += __shfl_down(sum, o); sumsq += __shfl_down(sumsq, o); }
    __shared__ float red[8];
    __shared__ float stats[2];
    const int w = tid >> 6;
    if ((tid & 63) == 0) { red[w] = sum; red[4 + w] = sumsq; }
    __syncthreads();
    if (tid == 0) {
        float s1 = red[0] + red[1] + red[2] + red[3];
        float s2 = red[4] + red[5] + red[6] + red[7];
        float mean = s1 * (1.f / 65536.f);
        float var  = s2 * (1.f / 65536.f) - mean * mean;
        stats[0] = mean; stats[1] = rsqrtf(var + GN_EPS);
    }
    __syncthreads();
    if (tid < 16) {
        const int ch = g * 16 + tid;
        const float sc = gs[ch] * stats[1];
        scA[b * 512 + ch] = sc;
        biA[b * 512 + ch] = gb[ch] - stats[0] * sc;
    }
}

// ---------------------------------------------------------------------------
// Fused GN-normalize + QKV GEMM.  A = x*sc+bi (fp32->bf16), B = wqkvT rows.
//   n in [0,1024): qk[m][n] = C + bias
//   n in [1024,1536): C+bias -> transposed into vT[b][ch][tok] via LDS
// 128x128 tile, BK=32, 4 waves. grid (M/128, 12), block 256.
// ---------------------------------------------------------------------------
__global__ __launch_bounds__(256)
void gemm_qkv(const float* __restrict__ x, const float* __restrict__ scA,
              const float* __restrict__ biA, const __bf16* __restrict__ Bt,
              const float* __restrict__ bias,
              __bf16* __restrict__ qk, __bf16* __restrict__ vT)
{
    const int bm = blockIdx.x * 128, bn = blockIdx.y * 128;
    const int tid = threadIdx.x;
    const int w = tid >> 6, lane = tid & 63, quad = lane >> 4, l15 = lane & 15;
    const int wm = (w >> 1) * 64, wn = (w & 1) * 64;
    const int brow = bm >> 12;                  // batch of this m-tile

    __shared__ __bf16 sAB[2][128][40];          // As = sAB[0], Bs = sAB[1]

    f32x4 acc[4][4];
#pragma unroll
    for (int i = 0; i < 4; ++i)
#pragma unroll
        for (int j = 0; j < 4; ++j) acc[i][j] = (f32x4){0.f, 0.f, 0.f, 0.f};

    const int sr = tid >> 2, scol = (tid & 3) * 8;
    for (int k0 = 0; k0 < 512; k0 += 32) {
        __syncthreads();
        {   // A: load fp32 x, apply GN scale/bias, stage bf16
            const float* scp = scA + brow * 512 + k0 + scol;
            const float* bip = biA + brow * 512 + k0 + scol;
            f32x4 s0v = *(const f32x4*)&scp[0], s1v = *(const f32x4*)&scp[4];
            f32x4 b0v = *(const f32x4*)&bip[0], b1v = *(const f32x4*)&bip[4];
            f32x4 xa0 = *(const f32x4*)&x[(size_t)(bm + sr) * 512 + k0 + scol];
            f32x4 xa1 = *(const f32x4*)&x[(size_t)(bm + sr) * 512 + k0 + scol + 4];
            f32x4 xb0 = *(const f32x4*)&x[(size_t)(bm + sr + 64) * 512 + k0 + scol];
            f32x4 xb1 = *(const f32x4*)&x[(size_t)(bm + sr + 64) * 512 + k0 + scol + 4];
            bfx8 ha, hb;
#pragma unroll
            for (int j = 0; j < 4; ++j) {
                ha[j]     = (__bf16)(xa0[j] * s0v[j] + b0v[j]);
                ha[4 + j] = (__bf16)(xa1[j] * s1v[j] + b1v[j]);
                hb[j]     = (__bf16)(xb0[j] * s0v[j] + b0v[j]);
                hb[4 + j] = (__bf16)(xb1[j] * s1v[j] + b1v[j]);
            }
            *(bfx8*)&sAB[0][sr][scol]      = ha;
            *(bfx8*)&sAB[0][sr + 64][scol] = hb;
        }
        *(bfx8*)&sAB[1][sr][scol]      = *(const bfx8*)&Bt[(size_t)(bn + sr) * 512 + k0 + scol];
        *(bfx8*)&sAB[1][sr + 64][scol] = *(const bfx8*)&Bt[(size_t)(bn + sr + 64) * 512 + k0 + scol];
        __syncthreads();
        bfx8 af[4], bfr[4];
#pragma unroll
        for (int mi = 0; mi < 4; ++mi) af[mi]  = *(const bfx8*)&sAB[0][wm + mi * 16 + l15][quad * 8];
#pragma unroll
        for (int ni = 0; ni < 4; ++ni) bfr[ni] = *(const bfx8*)&sAB[1][wn + ni * 16 + l15][quad * 8];
#pragma unroll
        for (int mi = 0; mi < 4; ++mi)
#pragma unroll
            for (int ni = 0; ni < 4; ++ni)
                acc[mi][ni] = MFMA16(af[mi], bfr[ni], acc[mi][ni]);
    }

    if (blockIdx.y < 8) {
        // q/k epilogue: direct store, D row = quad*4+reg, col = l15
#pragma unroll
        for (int ni = 0; ni < 4; ++ni) {
            const int col = bn + wn + ni * 16 + l15;
            const float bv = bias[col];
#pragma unroll
            for (int mi = 0; mi < 4; ++mi)
#pragma unroll
                for (int rr = 0; rr < 4; ++rr) {
                    const int row = bm + wm + mi * 16 + quad * 4 + rr;
                    qk[(size_t)row * 1024 + col] = (__bf16)(acc[mi][ni][rr] + bv);
                }
        }
    } else {
        // v epilogue: transpose 128x128 tile into vT[b][ch][tok] via LDS
        const int vch0 = bn - 1024;
        const int tokbase = bm & 4095;
        __bf16* tb = &sAB[0][0][0];             // reuse As+Bs: [64][136] bf16
        __syncthreads();                         // all waves done reading frags
#pragma unroll
        for (int chunk = 0; chunk < 2; ++chunk) {
            if ((w & 1) == chunk) {
#pragma unroll
                for (int ni = 0; ni < 4; ++ni) {
                    const int chc = ni * 16 + l15;               // 0..63 in chunk
                    const float bv = bias[bn + chunk * 64 + chc];
#pragma unroll
                    for (int mi = 0; mi < 4; ++mi)
#pragma unroll
                        for (int rr = 0; rr < 4; ++rr) {
                            const int tok = wm + mi * 16 + quad * 4 + rr;
                            tb[chc * 136 + tok] = (__bf16)(acc[mi][ni][rr] + bv);
                        }
                }
            }
            __syncthreads();
            {   // cooperative coalesced store of the 64ch x 128tok chunk
                const int chn = tid >> 2, t0 = (tid & 3) * 32;
                const size_t gb0 =
                    ((size_t)(brow * 512 + vch0 + chunk * 64 + chn)) * 4096 + tokbase;
#pragma unroll
                for (int u = 0; u < 4; ++u)
                    *(bfx8*)&vT[gb0 + t0 + u * 8] = *(const bfx8*)&tb[chn * 136 + t0 + u * 8];
            }
            __syncthreads();
        }
    }
}

// ---------------------------------------------------------------------------
// Flash attention + fused output projection + residual (fp32 out), v2.
// TQ=128 per block, 512 threads (8 waves), TK=32 per iter.
// S phase: wave w owns S rows [w*16,(w+1)*16) x 32 cols, Q in regs,
//          in-register online softmax (quad shfl reduce).
// PV phase: wave w owns O rows [(w&1)*64,+64) x cols [(w>>1)*128,+128).
// Staging software-pipelined: tile kt+1 global loads issued during kt compute.
// Epilogue: out = O*woT^T + bo + x, two 64-row half-passes via LDS.
// grid (NTOK/128, B), block 512.
// ---------------------------------------------------------------------------
__global__ __launch_bounds__(512, 2)
void attn_fused(const __bf16* __restrict__ qk, const __bf16* __restrict__ vT,
                const __bf16* __restrict__ woT, const float* __restrict__ bo,
                const float* __restrict__ x, float* __restrict__ out)
{
    const int bb = blockIdx.y;
    const int q0 = blockIdx.x * 128;
    const int tid = threadIdx.x;
    const int w = tid >> 6, lane = tid & 63, quad = lane >> 4, l15 = lane & 15;

    __shared__ __attribute__((aligned(16))) unsigned char smem[85504];
    __bf16 (*Ks)[520] = (__bf16(*)[520])smem;                 // 32x520  (33280 B)
    __bf16 (*Vs)[40]  = (__bf16(*)[40])(smem + 33280);        // 512x40  (40960 B)
    __bf16 (*Ph)[40]  = (__bf16(*)[40])(smem + 74240);        // 128x40  (10240 B)
    float* abuf = (float*)(smem + 84480);                     // 128 f32
    float* lbuf = (float*)(smem + 84992);                     // 128 f32
    __bf16 (*Obuf)[520] = (__bf16(*)[520])smem;               // 64x520 (66560B), post-loop

    // Q rows for this wave's S strip, full K=512, in registers (64 VGPRs)
    bfx8 qf[16];
    {
        const __bf16* qptr = qk + ((size_t)(bb * NTOK + q0 + w * 16 + l15)) * 1024;
#pragma unroll
        for (int kk = 0; kk < 16; ++kk)
            qf[kk] = *(const bfx8*)&qptr[kk * 32 + quad * 8];
    }

    f32x4 oacc[4][8];
#pragma unroll
    for (int i = 0; i < 4; ++i)
#pragma unroll
        for (int j = 0; j < 8; ++j) oacc[i][j] = (f32x4){0.f, 0.f, 0.f, 0.f};
    float mrow[4] = {-1e30f, -1e30f, -1e30f, -1e30f};
    float lrow[4] = {0.f, 0.f, 0.f, 0.f};

    // staging assignments (512 threads)
    const int krow = tid >> 4, kcol = (tid & 15) * 32;   // K: 32 rows x 512 ch
    const int vch  = tid;                                // V^T: 512 ch x 32 tok
    const __bf16* kbase = qk + ((size_t)(bb * NTOK + krow)) * 1024 + 512 + kcol;
    const __bf16* vbase = vT + ((size_t)(bb * 512 + vch)) * NTOK;

    // prefetch tile 0 into registers (32 VGPRs)
    bfx8 kreg[4], vreg[4];
#pragma unroll
    for (int u = 0; u < 4; ++u) kreg[u] = *(const bfx8*)&kbase[u * 8];
#pragma unroll
    for (int u = 0; u < 4; ++u) vreg[u] = *(const bfx8*)&vbase[u * 8];

    const int rh = (w & 1) * 64;       // PV row-half base
    const int cq = (w >> 1) * 128;     // PV col-quarter base

    for (int kt = 0; kt < NTOK / 32; ++kt) {
        // stage prefetched tile into LDS (waits vmcnt on kreg/vreg)
#pragma unroll
        for (int u = 0; u < 4; ++u) *(bfx8*)&Ks[krow][kcol + u * 8] = kreg[u];
#pragma unroll
        for (int u = 0; u < 4; ++u) *(bfx8*)&Vs[vch][u * 8] = vreg[u];
        __syncthreads();

        // issue global loads for next tile (hidden under S+softmax+PV compute)
        {
            const int ktn = (kt < NTOK / 32 - 1) ? kt + 1 : kt;
            const __bf16* kp = kbase + (size_t)ktn * 32 * 1024;
            const __bf16* vp = vbase + ktn * 32;
#pragma unroll
            for (int u = 0; u < 4; ++u) kreg[u] = *(const bfx8*)&kp[u * 8];
#pragma unroll
            for (int u = 0; u < 4; ++u) vreg[u] = *(const bfx8*)&vp[u * 8];
        }

        // S strip: rows [w*16,w*16+16) x 32 cols
        f32x4 s0 = (f32x4){0.f, 0.f, 0.f, 0.f}, s1 = (f32x4){0.f, 0.f, 0.f, 0.f};
#pragma unroll
        for (int kk = 0; kk < 16; ++kk) {
            bfx8 kb0 = *(const bfx8*)&Ks[l15][kk * 32 + quad * 8];
            bfx8 kb1 = *(const bfx8*)&Ks[16 + l15][kk * 32 + quad * 8];
            s0 = MFMA16(qf[kk], kb0, s0);
            s1 = MFMA16(qf[kk], kb1, s1);
        }
        // online softmax per row (row = w*16 + quad*4 + r)
#pragma unroll
        for (int r = 0; r < 4; ++r) {
            float v0 = s0[r] * ATT_SCALE;
            float v1 = s1[r] * ATT_SCALE;
            float mx = fmaxf(v0, v1);
#pragma unroll
            for (int o = 1; o < 16; o <<= 1) mx = fmaxf(mx, __shfl_xor(mx, o));
            const float mnew = fmaxf(mrow[r], mx);
            const float al = __expf(mrow[r] - mnew);
            const float p0 = __expf(v0 - mnew);
            const float p1 = __expf(v1 - mnew);
            float ps = p0 + p1;
#pragma unroll
            for (int o = 1; o < 16; o <<= 1) ps += __shfl_xor(ps, o);
            lrow[r] = lrow[r] * al + ps;
            mrow[r] = mnew;
            const int row = w * 16 + quad * 4 + r;
            Ph[row][l15]      = (__bf16)p0;
            Ph[row][16 + l15] = (__bf16)p1;
            if (l15 == 0) abuf[row] = al;
        }
        __syncthreads();

        // O *= alpha;  O += P*V  (rows rh..rh+64, cols cq..cq+128)
#pragma unroll
        for (int mt = 0; mt < 4; ++mt)
#pragma unroll
            for (int r = 0; r < 4; ++r) {
                const float al = abuf[rh + mt * 16 + quad * 4 + r];
#pragma unroll
                for (int ct = 0; ct < 8; ++ct) oacc[mt][ct][r] *= al;
            }
        bfx8 pa[4];
#pragma unroll
        for (int mt = 0; mt < 4; ++mt)
            pa[mt] = *(const bfx8*)&Ph[rh + mt * 16 + l15][quad * 8];
#pragma unroll
        for (int ct = 0; ct < 8; ++ct) {
            bfx8 vb = *(const bfx8*)&Vs[cq + ct * 16 + l15][quad * 8];
#pragma unroll
            for (int mt = 0; mt < 4; ++mt)
                oacc[mt][ct] = MFMA16(pa[mt], vb, oacc[mt][ct]);
        }
        __syncthreads();   // PV LDS reads done before next restage
    }

    // ---- epilogue: normalize + projection + bias + residual, 2 half-passes --
    if (l15 == 0) {
#pragma unroll
        for (int r = 0; r < 4; ++r) lbuf[w * 16 + quad * 4 + r] = lrow[r];
    }

#pragma unroll
    for (int h = 0; h < 2; ++h) {
        __syncthreads();   // lbuf visible (h=0) / prev half's Obuf reads done
        if ((w & 1) == h) {
#pragma unroll
            for (int mt = 0; mt < 4; ++mt)
#pragma unroll
                for (int r = 0; r < 4; ++r) {
                    const int rl = mt * 16 + quad * 4 + r;       // 0..63
                    const float linv = 1.f / lbuf[h * 64 + rl];
#pragma unroll
                    for (int ct = 0; ct < 8; ++ct)
                        Obuf[rl][cq + ct * 16 + l15] = (__bf16)(oacc[mt][ct][r] * linv);
                }
        }
        __syncthreads();

        // project rows [h*64, h*64+64): wave strip rows (w&3)*16, cols (w>>2)*256
        const int rs  = (w & 3) * 16;
        const int nt0 = (w >> 2) * 16;
        bfx8 af2[16];
#pragma unroll
        for (int k0 = 0; k0 < 16; ++k0)
            af2[k0] = *(const bfx8*)&Obuf[rs + l15][k0 * 32 + quad * 8];
#pragma unroll 4
        for (int nt = 0; nt < 16; ++nt) {
            f32x4 a2 = (f32x4){0.f, 0.f, 0.f, 0.f};
#pragma unroll
            for (int k0 = 0; k0 < 16; ++k0) {
                bfx8 wb = *(const bfx8*)&woT[(size_t)((nt0 + nt) * 16 + l15) * 512 + k0 * 32 + quad * 8];
                a2 = MFMA16(af2[k0], wb, a2);
            }
            const int col = (nt0 + nt) * 16 + l15;
            const float bv = bo[col];
#pragma unroll
            for (int rr = 0; rr < 4; ++rr) {
                const size_t idx =
                    ((size_t)(bb * NTOK + q0 + h * 64 + rs + quad * 4 + rr)) * 512 + col;
                out[idx] = a2[rr] + bv + x[idx];
            }
        }
    }
}

// ---------------------------------------------------------------------------
extern "C" void kernel_launch(void* const* d_in, const int* in_sizes, int n_in,
                              void* d_out, int out_size, void* d_ws, size_t ws_size,
                              hipStream_t stream)
{
    const float* x  = (const float*)d_in[0];
    const float* gs = (const float*)d_in[1];
    const float* gb = (const float*)d_in[2];
    const float* wq = (const float*)d_in[3];
    const float* bq = (const float*)d_in[4];
    const float* wk = (const float*)d_in[5];
    const float* bk = (const float*)d_in[6];
    const float* wv = (const float*)d_in[7];
    const float* bv = (const float*)d_in[8];
    const float* wo = (const float*)d_in[9];
    const float* bo = (const float*)d_in[10];
    float* out = (float*)d_out;

    // workspace layout -- total 102,799,360 B (~98 MiB)
    char* ws = (char*)d_ws;
    __bf16* qk    = (__bf16*)(ws);                    //  67,108,864 B [32768][1024]
    __bf16* vT    = (__bf16*)(ws + 67108864);         //  33,554,432 B [8][512][4096]
    __bf16* wqkvT = (__bf16*)(ws + 100663296);        //   1,572,864 B [1536][512]
    __bf16* woT   = (__bf16*)(ws + 102236160);        //     524,288 B [512][512]
    float*  bqkv  = (float* )(ws + 102760448);        //       6,144 B [1536]
    float*  scA   = (float* )(ws + 102766592);        //      16,384 B [8][512]
    float*  biA   = (float* )(ws + 102782976);        //      16,384 B [8][512]

    prep_weights<<<dim3(16, 16, 4), 256, 0, stream>>>(wq, wk, wv, wo, bq, bk, bv,
                                                      wqkvT, woT, bqkv);
    gn_stats<<<dim3(32, BATCH), 256, 0, stream>>>(x, gs, gb, scA, biA);
    gemm_qkv<<<dim3(256, 12), 256, 0, stream>>>(x, scA, biA, wqkvT, bqkv, qk, vT);
    attn_fused<<<dim3(NTOK / 128, BATCH), 512, 0, stream>>>(qk, vT, woT, bo, x, out);
}

// Round 5
// 863.472 us; speedup vs baseline: 1.8543x; 1.3896x over previous
//
#include <hip/hip_runtime.h>

typedef __bf16 bfx8 __attribute__((ext_vector_type(8)));
typedef __bf16 bfx4 __attribute__((ext_vector_type(4)));
typedef float  f32x4 __attribute__((ext_vector_type(4)));

#define MFMA16(a,b,c) __builtin_amdgcn_mfma_f32_16x16x32_bf16((a),(b),(c),0,0,0)

static constexpr int BATCH = 8;
static constexpr int NTOK  = 4096;   // 64*64 spatial
static constexpr int CH    = 512;
static constexpr float GN_EPS = 1e-5f;
static constexpr float ATT_SCALE = 0.044194173824159216f; // 512^-0.5

// ---------------------------------------------------------------------------
// prep: fp32 weights -> bf16 transposed (wT[n][c] = w[c][n]); concat fp32 biases.
// grid (16,16,4) z: 0=wq 1=wk 2=wv 3=wo. block 256.
// ---------------------------------------------------------------------------
__global__ __launch_bounds__(256)
void prep_weights(const float* __restrict__ wq, const float* __restrict__ wk,
                  const float* __restrict__ wv, const float* __restrict__ wo,
                  const float* __restrict__ bq, const float* __restrict__ bk,
                  const float* __restrict__ bv,
                  __bf16* __restrict__ wqkvT, __bf16* __restrict__ woT,
                  float* __restrict__ bqkv)
{
    __shared__ __bf16 t[32][36];
    const int z  = blockIdx.z;
    const float* src = (z == 0) ? wq : (z == 1) ? wk : (z == 2) ? wv : wo;
    const int c0 = blockIdx.x * 32, n0 = blockIdx.y * 32;
    const int tid = threadIdx.x;
    const int r = tid >> 3, c4 = (tid & 7) * 4;

    f32x4 in = *(const f32x4*)&src[(size_t)(c0 + r) * 512 + n0 + c4];
    bfx4 tv;
#pragma unroll
    for (int i = 0; i < 4; ++i) tv[i] = (__bf16)in[i];
    *(bfx4*)&t[r][c4] = tv;
    __syncthreads();
    bfx4 o;
#pragma unroll
    for (int i = 0; i < 4; ++i) o[i] = t[c4 + i][r];
    if (z < 3)
        *(bfx4*)&wqkvT[((size_t)(z * 512 + n0 + r)) * 512 + c0 + c4] = o;
    else
        *(bfx4*)&woT[((size_t)(n0 + r)) * 512 + c0 + c4] = o;

    if (z < 3 && blockIdx.x == 0 && blockIdx.y == 0) {
        const float* bs = (z == 0) ? bq : (z == 1) ? bk : bv;
        bqkv[z * 512 + tid]       = bs[tid];
        bqkv[z * 512 + tid + 256] = bs[tid + 256];
    }
}

// ---------------------------------------------------------------------------
// GroupNorm statistics: one block per (g, b). Writes per-channel fused
// scale/bias:  h[ch] = x[ch]*scA[b][ch] + biA[b][ch].  grid (32, 8), block 256.
// ---------------------------------------------------------------------------
__global__ __launch_bounds__(256)
void gn_stats(const float* __restrict__ x, const float* __restrict__ gs,
              const float* __restrict__ gb,
              float* __restrict__ scA, float* __restrict__ biA)
{
    const int g = blockIdx.x, b = blockIdx.y;
    const int tid = threadIdx.x;
    const int half = tid & 1;
    const size_t base = (size_t)b * NTOK * CH + g * 16 + half * 8;

    float sum = 0.f, sumsq = 0.f;
    for (int i = tid; i < 2 * NTOK; i += 256) {
        const int s = i >> 1;
        f32x4 v0 = *(const f32x4*)&x[base + (size_t)s * CH];
        f32x4 v1 = *(const f32x4*)&x[base + (size_t)s * CH + 4];
#pragma unroll
        for (int j = 0; j < 4; ++j) {
            sum += v0[j] + v1[j];
            sumsq += v0[j] * v0[j] + v1[j] * v1[j];
        }
    }
#pragma unroll
    for (int o = 32; o; o >>= 1) { sum += __shfl_down(sum, o); sumsq += __shfl_down(sumsq, o); }
    __shared__ float red[8];
    __shared__ float stats[2];
    const int w = tid >> 6;
    if ((tid & 63) == 0) { red[w] = sum; red[4 + w] = sumsq; }
    __syncthreads();
    if (tid == 0) {
        float s1 = red[0] + red[1] + red[2] + red[3];
        float s2 = red[4] + red[5] + red[6] + red[7];
        float mean = s1 * (1.f / 65536.f);
        float var  = s2 * (1.f / 65536.f) - mean * mean;
        stats[0] = mean; stats[1] = rsqrtf(var + GN_EPS);
    }
    __syncthreads();
    if (tid < 16) {
        const int ch = g * 16 + tid;
        const float sc = gs[ch] * stats[1];
        scA[b * 512 + ch] = sc;
        biA[b * 512 + ch] = gb[ch] - stats[0] * sc;
    }
}

// ---------------------------------------------------------------------------
// Fused GN-normalize + QKV GEMM.  A = x*sc+bi (fp32->bf16), B = wqkvT rows.
//   n in [0,1024): qk[m][n] = C + bias
//   n in [1024,1536): C+bias -> transposed into vT[b][ch][tok] via LDS
// 128x128 tile, BK=32, 4 waves. grid (M/128, 12), block 256.
// ---------------------------------------------------------------------------
__global__ __launch_bounds__(256)
void gemm_qkv(const float* __restrict__ x, const float* __restrict__ scA,
              const float* __restrict__ biA, const __bf16* __restrict__ Bt,
              const float* __restrict__ bias,
              __bf16* __restrict__ qk, __bf16* __restrict__ vT)
{
    const int bm = blockIdx.x * 128, bn = blockIdx.y * 128;
    const int tid = threadIdx.x;
    const int w = tid >> 6, lane = tid & 63, quad = lane >> 4, l15 = lane & 15;
    const int wm = (w >> 1) * 64, wn = (w & 1) * 64;
    const int brow = bm >> 12;                  // batch of this m-tile

    __shared__ __bf16 sAB[2][128][40];          // As = sAB[0], Bs = sAB[1]

    f32x4 acc[4][4];
#pragma unroll
    for (int i = 0; i < 4; ++i)
#pragma unroll
        for (int j = 0; j < 4; ++j) acc[i][j] = (f32x4){0.f, 0.f, 0.f, 0.f};

    const int sr = tid >> 2, scol = (tid & 3) * 8;
    for (int k0 = 0; k0 < 512; k0 += 32) {
        __syncthreads();
        {   // A: load fp32 x, apply GN scale/bias, stage bf16
            const float* scp = scA + brow * 512 + k0 + scol;
            const float* bip = biA + brow * 512 + k0 + scol;
            f32x4 s0v = *(const f32x4*)&scp[0], s1v = *(const f32x4*)&scp[4];
            f32x4 b0v = *(const f32x4*)&bip[0], b1v = *(const f32x4*)&bip[4];
            f32x4 xa0 = *(const f32x4*)&x[(size_t)(bm + sr) * 512 + k0 + scol];
            f32x4 xa1 = *(const f32x4*)&x[(size_t)(bm + sr) * 512 + k0 + scol + 4];
            f32x4 xb0 = *(const f32x4*)&x[(size_t)(bm + sr + 64) * 512 + k0 + scol];
            f32x4 xb1 = *(const f32x4*)&x[(size_t)(bm + sr + 64) * 512 + k0 + scol + 4];
            bfx8 ha, hb;
#pragma unroll
            for (int j = 0; j < 4; ++j) {
                ha[j]     = (__bf16)(xa0[j] * s0v[j] + b0v[j]);
                ha[4 + j] = (__bf16)(xa1[j] * s1v[j] + b1v[j]);
                hb[j]     = (__bf16)(xb0[j] * s0v[j] + b0v[j]);
                hb[4 + j] = (__bf16)(xb1[j] * s1v[j] + b1v[j]);
            }
            *(bfx8*)&sAB[0][sr][scol]      = ha;
            *(bfx8*)&sAB[0][sr + 64][scol] = hb;
        }
        *(bfx8*)&sAB[1][sr][scol]      = *(const bfx8*)&Bt[(size_t)(bn + sr) * 512 + k0 + scol];
        *(bfx8*)&sAB[1][sr + 64][scol] = *(const bfx8*)&Bt[(size_t)(bn + sr + 64) * 512 + k0 + scol];
        __syncthreads();
        bfx8 af[4], bfr[4];
#pragma unroll
        for (int mi = 0; mi < 4; ++mi) af[mi]  = *(const bfx8*)&sAB[0][wm + mi * 16 + l15][quad * 8];
#pragma unroll
        for (int ni = 0; ni < 4; ++ni) bfr[ni] = *(const bfx8*)&sAB[1][wn + ni * 16 + l15][quad * 8];
#pragma unroll
        for (int mi = 0; mi < 4; ++mi)
#pragma unroll
            for (int ni = 0; ni < 4; ++ni)
                acc[mi][ni] = MFMA16(af[mi], bfr[ni], acc[mi][ni]);
    }

    if (blockIdx.y < 8) {
        // q/k epilogue: direct store, D row = quad*4+reg, col = l15
#pragma unroll
        for (int ni = 0; ni < 4; ++ni) {
            const int col = bn + wn + ni * 16 + l15;
            const float bv = bias[col];
#pragma unroll
            for (int mi = 0; mi < 4; ++mi)
#pragma unroll
                for (int rr = 0; rr < 4; ++rr) {
                    const int row = bm + wm + mi * 16 + quad * 4 + rr;
                    qk[(size_t)row * 1024 + col] = (__bf16)(acc[mi][ni][rr] + bv);
                }
        }
    } else {
        // v epilogue: transpose 128x128 tile into vT[b][ch][tok] via LDS
        const int vch0 = bn - 1024;
        const int tokbase = bm & 4095;
        __bf16* tb = &sAB[0][0][0];             // reuse As+Bs: [64][136] bf16
        __syncthreads();                         // all waves done reading frags
#pragma unroll
        for (int chunk = 0; chunk < 2; ++chunk) {
            if ((w & 1) == chunk) {
#pragma unroll
                for (int ni = 0; ni < 4; ++ni) {
                    const int chc = ni * 16 + l15;               // 0..63 in chunk
                    const float bv = bias[bn + chunk * 64 + chc];
#pragma unroll
                    for (int mi = 0; mi < 4; ++mi)
#pragma unroll
                        for (int rr = 0; rr < 4; ++rr) {
                            const int tok = wm + mi * 16 + quad * 4 + rr;
                            tb[chc * 136 + tok] = (__bf16)(acc[mi][ni][rr] + bv);
                        }
                }
            }
            __syncthreads();
            {   // cooperative coalesced store of the 64ch x 128tok chunk
                const int chn = tid >> 2, t0 = (tid & 3) * 32;
                const size_t gb0 =
                    ((size_t)(brow * 512 + vch0 + chunk * 64 + chn)) * 4096 + tokbase;
#pragma unroll
                for (int u = 0; u < 4; ++u)
                    *(bfx8*)&vT[gb0 + t0 + u * 8] = *(const bfx8*)&tb[chn * 136 + t0 + u * 8];
            }
            __syncthreads();
        }
    }
}

// ---------------------------------------------------------------------------
// Flash attention + fused output projection + residual (fp32 out), v3.
// TQ=128 per block, 512 threads (8 waves), TK=32 per iter.
// S computed TRANSPOSED: mfma(a=K rows, b=Q rows) -> St[j=quad*4+reg][m=l15].
//   Softmax over j = 3 local fmax + 2 shfl_xor (16,32) instead of 8 shfls/row.
//   P packed per-lane -> 2 ds_write_b64 into Ph[m][j]; alpha -> abuf.
// PV (after barrier): wave w does O rows [(w&1)*64,+64) x cols [(w>>1)*128,+128),
//   rescale skipped via block-wide flag when no lane saw a new max.
// Staging: lane-contiguous 16B rows (conflict-free), double-issue prefetch.
// Epilogue: out = O*woT^T + bo + x, two 64-row half-passes via LDS.
// grid (NTOK/128, B), block 512.
// ---------------------------------------------------------------------------
__global__ __launch_bounds__(512, 2)
void attn_fused(const __bf16* __restrict__ qk, const __bf16* __restrict__ vT,
                const __bf16* __restrict__ woT, const float* __restrict__ bo,
                const float* __restrict__ x, float* __restrict__ out)
{
    const int bb = blockIdx.y;
    const int q0 = blockIdx.x * 128;
    const int tid = threadIdx.x;
    const int w = tid >> 6, lane = tid & 63, quad = lane >> 4, l15 = lane & 15;

    __shared__ __attribute__((aligned(16))) unsigned char smem[85520];
    __bf16 (*Ks)[520] = (__bf16(*)[520])smem;                 // 32x520  (33280 B)
    __bf16 (*Vs)[40]  = (__bf16(*)[40])(smem + 33280);        // 512x40  (40960 B)
    __bf16 (*Ph)[40]  = (__bf16(*)[40])(smem + 74240);        // 128x40  (10240 B)
    float* abuf  = (float*)(smem + 84480);                    // 128 f32
    float* lbuf  = (float*)(smem + 84992);                    // 128 f32
    int*   rflag = (int*)(smem + 85504);                      // 2 ints
    __bf16 (*Obuf)[520] = (__bf16(*)[520])smem;               // 64x520 (66560B), post-loop

    // Q rows for this wave's Sᵀ columns, full K=512, in registers (64 VGPRs)
    bfx8 qf[16];
    {
        const __bf16* qptr = qk + ((size_t)(bb * NTOK + q0 + w * 16 + l15)) * 1024;
#pragma unroll
        for (int kk = 0; kk < 16; ++kk)
            qf[kk] = *(const bfx8*)&qptr[kk * 32 + quad * 8];
    }

    f32x4 oacc[4][8];
#pragma unroll
    for (int i = 0; i < 4; ++i)
#pragma unroll
        for (int j = 0; j < 8; ++j) oacc[i][j] = (f32x4){0.f, 0.f, 0.f, 0.f};
    // online-softmax state per lane: column m = w*16 + l15 (replicated over quads)
    float mcur = -1e30f, lcur = 0.f;

    // staging: wave w stages K rows [w*4, w*4+4), each lane 16 contiguous bytes
    const __bf16* kbase = qk + ((size_t)(bb * NTOK) + w * 4) * 1024 + 512 + lane * 8;
    // V^T: wave w stages ch [w*64, w*64+64), 4 lanes per ch row (16 B each)
    const __bf16* vbase = vT + ((size_t)(bb * 512 + w * 64 + (lane >> 2))) * 4096 + (lane & 3) * 8;

    bfx8 kreg[4], vreg[4];
#pragma unroll
    for (int u = 0; u < 4; ++u) kreg[u] = *(const bfx8*)&kbase[u * 1024];
#pragma unroll
    for (int u = 0; u < 4; ++u) vreg[u] = *(const bfx8*)&vbase[(size_t)u * 16 * 4096];

    const int rh = (w & 1) * 64;       // PV row-half base
    const int cq = (w >> 1) * 128;     // PV col-quarter base

    for (int kt = 0; kt < NTOK / 32; ++kt) {
        // stage prefetched tile (lane-contiguous, conflict-free)
#pragma unroll
        for (int u = 0; u < 4; ++u) *(bfx8*)&Ks[w * 4 + u][lane * 8] = kreg[u];
#pragma unroll
        for (int u = 0; u < 4; ++u)
            *(bfx8*)&Vs[w * 64 + u * 16 + (lane >> 2)][(lane & 3) * 8] = vreg[u];
        __syncthreads();                                     // barrier A

        // issue next tile's global loads (drain during compute)
        {
            const int ktn = (kt < NTOK / 32 - 1) ? kt + 1 : kt;
            const __bf16* kp = kbase + (size_t)ktn * 32 * 1024;
            const __bf16* vp = vbase + ktn * 32;
#pragma unroll
            for (int u = 0; u < 4; ++u) kreg[u] = *(const bfx8*)&kp[u * 1024];
#pragma unroll
            for (int u = 0; u < 4; ++u) vreg[u] = *(const bfx8*)&vp[(size_t)u * 16 * 4096];
        }

        // Sᵀ: s0 = St[j=quad*4+r][m], j in [0,16); s1: j in [16,32)
        f32x4 s0 = (f32x4){0.f, 0.f, 0.f, 0.f}, s1 = (f32x4){0.f, 0.f, 0.f, 0.f};
#pragma unroll
        for (int kk = 0; kk < 16; ++kk) {
            bfx8 kb0 = *(const bfx8*)&Ks[l15][kk * 32 + quad * 8];
            bfx8 kb1 = *(const bfx8*)&Ks[16 + l15][kk * 32 + quad * 8];
            s0 = MFMA16(kb0, qf[kk], s0);
            s1 = MFMA16(kb1, qf[kk], s1);
        }

        // softmax over j for column m=l15: local max/sum + 2 quad shfls
        {
            float mx = -1e30f;
#pragma unroll
            for (int i = 0; i < 4; ++i) {
                s0[i] *= ATT_SCALE; s1[i] *= ATT_SCALE;
                mx = fmaxf(mx, fmaxf(s0[i], s1[i]));
            }
            mx = fmaxf(mx, __shfl_xor(mx, 16));
            mx = fmaxf(mx, __shfl_xor(mx, 32));
            const float mnew = fmaxf(mcur, mx);
            const float al = __expf(mcur - mnew);
            float ps = 0.f;
            bfx4 pl0, pl1;
#pragma unroll
            for (int i = 0; i < 4; ++i) {
                float p = __expf(s0[i] - mnew); ps += p; pl0[i] = (__bf16)p;
            }
#pragma unroll
            for (int i = 0; i < 4; ++i) {
                float p = __expf(s1[i] - mnew); ps += p; pl1[i] = (__bf16)p;
            }
            ps += __shfl_xor(ps, 16);
            ps += __shfl_xor(ps, 32);
            lcur = lcur * al + ps;
            mcur = mnew;
            *(bfx4*)&Ph[w * 16 + l15][quad * 4]      = pl0;
            *(bfx4*)&Ph[w * 16 + l15][16 + quad * 4] = pl1;
            if (quad == 0) abuf[w * 16 + l15] = al;
            if (__ballot(al != 1.0f)) { if (lane == 0) rflag[kt & 1] = 1; }
            if (tid == 0) rflag[(kt + 1) & 1] = 0;
        }
        __syncthreads();                                     // barrier B

        // conditional O rescale (skipped once running max stabilizes)
        if (rflag[kt & 1]) {
#pragma unroll
            for (int mt = 0; mt < 4; ++mt)
#pragma unroll
                for (int r = 0; r < 4; ++r) {
                    const float al = abuf[rh + mt * 16 + quad * 4 + r];
#pragma unroll
                    for (int ct = 0; ct < 8; ++ct) oacc[mt][ct][r] *= al;
                }
        }
        // O += P*V  (rows rh..rh+64, cols cq..cq+128)
        bfx8 pa[4];
#pragma unroll
        for (int mt = 0; mt < 4; ++mt)
            pa[mt] = *(const bfx8*)&Ph[rh + mt * 16 + l15][quad * 8];
#pragma unroll
        for (int ct = 0; ct < 8; ++ct) {
            bfx8 vb = *(const bfx8*)&Vs[cq + ct * 16 + l15][quad * 8];
#pragma unroll
            for (int mt = 0; mt < 4; ++mt)
                oacc[mt][ct] = MFMA16(pa[mt], vb, oacc[mt][ct]);
        }
        __syncthreads();                                     // barrier C
    }

    // ---- epilogue: normalize + projection + bias + residual, 2 half-passes --
    if (quad == 0) lbuf[w * 16 + l15] = lcur;

#pragma unroll
    for (int h = 0; h < 2; ++h) {
        __syncthreads();   // lbuf visible (h=0) / prev half's Obuf reads done
        if ((w & 1) == h) {
#pragma unroll
            for (int mt = 0; mt < 4; ++mt)
#pragma unroll
                for (int r = 0; r < 4; ++r) {
                    const int rl = mt * 16 + quad * 4 + r;       // 0..63
                    const float linv = 1.f / lbuf[h * 64 + rl];
#pragma unroll
                    for (int ct = 0; ct < 8; ++ct)
                        Obuf[rl][cq + ct * 16 + l15] = (__bf16)(oacc[mt][ct][r] * linv);
                }
        }
        __syncthreads();

        // project rows [h*64, h*64+64): wave strip rows (w&3)*16, cols (w>>2)*256
        const int rs  = (w & 3) * 16;
        const int nt0 = (w >> 2) * 16;
        bfx8 af2[16];
#pragma unroll
        for (int k0 = 0; k0 < 16; ++k0)
            af2[k0] = *(const bfx8*)&Obuf[rs + l15][k0 * 32 + quad * 8];
#pragma unroll 4
        for (int nt = 0; nt < 16; ++nt) {
            f32x4 a2 = (f32x4){0.f, 0.f, 0.f, 0.f};
#pragma unroll
            for (int k0 = 0; k0 < 16; ++k0) {
                bfx8 wb = *(const bfx8*)&woT[(size_t)((nt0 + nt) * 16 + l15) * 512 + k0 * 32 + quad * 8];
                a2 = MFMA16(af2[k0], wb, a2);
            }
            const int col = (nt0 + nt) * 16 + l15;
            const float bv = bo[col];
#pragma unroll
            for (int rr = 0; rr < 4; ++rr) {
                const size_t idx =
                    ((size_t)(bb * NTOK + q0 + h * 64 + rs + quad * 4 + rr)) * 512 + col;
                out[idx] = a2[rr] + bv + x[idx];
            }
        }
    }
}

// ---------------------------------------------------------------------------
extern "C" void kernel_launch(void* const* d_in, const int* in_sizes, int n_in,
                              void* d_out, int out_size, void* d_ws, size_t ws_size,
                              hipStream_t stream)
{
    const float* x  = (const float*)d_in[0];
    const float* gs = (const float*)d_in[1];
    const float* gb = (const float*)d_in[2];
    const float* wq = (const float*)d_in[3];
    const float* bq = (const float*)d_in[4];
    const float* wk = (const float*)d_in[5];
    const float* bk = (const float*)d_in[6];
    const float* wv = (const float*)d_in[7];
    const float* bv = (const float*)d_in[8];
    const float* wo = (const float*)d_in[9];
    const float* bo = (const float*)d_in[10];
    float* out = (float*)d_out;

    // workspace layout -- total 102,799,360 B (~98 MiB)
    char* ws = (char*)d_ws;
    __bf16* qk    = (__bf16*)(ws);                    //  67,108,864 B [32768][1024]
    __bf16* vT    = (__bf16*)(ws + 67108864);         //  33,554,432 B [8][512][4096]
    __bf16* wqkvT = (__bf16*)(ws + 100663296);        //   1,572,864 B [1536][512]
    __bf16* woT   = (__bf16*)(ws + 102236160);        //     524,288 B [512][512]
    float*  bqkv  = (float* )(ws + 102760448);        //       6,144 B [1536]
    float*  scA   = (float* )(ws + 102766592);        //      16,384 B [8][512]
    float*  biA   = (float* )(ws + 102782976);        //      16,384 B [8][512]

    prep_weights<<<dim3(16, 16, 4), 256, 0, stream>>>(wq, wk, wv, wo, bq, bk, bv,
                                                      wqkvT, woT, bqkv);
    gn_stats<<<dim3(32, BATCH), 256, 0, stream>>>(x, gs, gb, scA, biA);
    gemm_qkv<<<dim3(256, 12), 256, 0, stream>>>(x, scA, biA, wqkvT, bqkv, qk, vT);
    attn_fused<<<dim3(NTOK / 128, BATCH), 512, 0, stream>>>(qk, vT, woT, bo, x, out);
}